// Round 2
// baseline (553.373 us; speedup 1.0000x reference)
//
#include <hip/hip_runtime.h>
#include <hip/hip_bf16.h>

#define HID 1024
#define HEADS 16
#define HEAD 64
#define RELN 63
#define SEQ 512
#define BATCH 16
#define NROWS (SEQ*BATCH)      // 8192
#define MEXT 8320              // 8192 + 63, padded to 65*128
#define NQKV 3072
#define LNEPS 1e-7f

typedef __attribute__((ext_vector_type(4))) float  f32x4;
typedef __attribute__((ext_vector_type(8))) short  s16x8;
typedef __attribute__((ext_vector_type(4))) ushort u16x4;

static __device__ __forceinline__ ushort f2bf(float f) {
  union { float f; unsigned u; } v; v.f = f;
  unsigned r = v.u + 0x7fffu + ((v.u >> 16) & 1u);
  return (ushort)(r >> 16);
}
static __device__ __forceinline__ float bf2f(ushort u) {
  union { unsigned u; float f; } v; v.u = ((unsigned)u) << 16;
  return v.f;
}

// ---------------- prep: mask dtype detect + mask bias + bucket idx table + bias concat ----
__global__ void k_prep(const void* mask_raw, const float* bqk, const float* bv,
                       float* maskbias, int* idx_tab, float* bcat) {
  __shared__ int s_isbool;
  int tid = threadIdx.x;
  if (tid == 0) s_isbool = 0;
  __syncthreads();
  const unsigned* mu = (const unsigned*)mask_raw;
  int bad = 0;
  for (int i = tid; i < 2048; i += 256) if (mu[i] > 1u) bad = 1;
  if (bad) s_isbool = 1;              // benign race: any writer writes 1
  __syncthreads();
  int isbool = s_isbool;
  const unsigned char* m8 = (const unsigned char*)mask_raw;
  const int* m32 = (const int*)mask_raw;
  for (int i = tid; i < BATCH*SEQ; i += 256) {
    int m = isbool ? (int)m8[i] : m32[i];
    maskbias[i] = m ? -1e9f : 0.0f;
  }
  for (int i = tid; i < 1023; i += 256) {
    int r = i - 511;
    int a = r < 0 ? -r : r;
    int absp = (a < 16) ? 15 : (a < 511 ? a : 511);
    int idx;
    if (absp <= 16) idx = 31 + r;
    else {
      float v = logf((float)absp / 16.0f) / logf(511.0f / 16.0f) * 15.0f;
      int lp = (int)ceilf(v) + 16;
      idx = 31 + (r > 0 ? lp : -lp);
    }
    idx_tab[i] = idx;
  }
  for (int i = tid; i < 2048; i += 256) bcat[i] = bqk[i];
  for (int i = tid; i < 1024; i += 256) bcat[2048 + i] = bv[i];
}

// ---------------- f32 -> bf16 weight conversion (wqk|wv concat, wo) ----------------------
__global__ void k_convert(const float* wqk, const float* wv, const float* wo,
                          ushort* wcat, ushort* wo_b) {
  int i = blockIdx.x * 256 + threadIdx.x;
  if (i < 2048 * 1024) wcat[i] = f2bf(wqk[i]);
  else if (i < 3072 * 1024) wcat[i] = f2bf(wv[i - 2048 * 1024]);
  if (i < 1024 * 1024) wo_b[i] = f2bf(wo[i]);
}

// ---------------- LN1 (no affine) -> bf16, plus rel-embedding rows + zero pad ------------
__global__ __launch_bounds__(256) void k_ln1(const float* hid, const float* rel, ushort* h_ext) {
  int row = blockIdx.x, tid = threadIdx.x;
  __shared__ float red[8];
  if (row < NROWS) {
    const float* src = hid + (size_t)row * HID;
    f32x4 x = *(const f32x4*)(src + tid * 4);
    float s = x[0] + x[1] + x[2] + x[3];
    #pragma unroll
    for (int m = 1; m < 64; m <<= 1) s += __shfl_xor(s, m);
    if ((tid & 63) == 0) red[tid >> 6] = s;
    __syncthreads();
    float mean = (red[0] + red[1] + red[2] + red[3]) * (1.0f / HID);
    float d0 = x[0] - mean, d1 = x[1] - mean, d2 = x[2] - mean, d3 = x[3] - mean;
    float sq = d0*d0 + d1*d1 + d2*d2 + d3*d3;
    #pragma unroll
    for (int m = 1; m < 64; m <<= 1) sq += __shfl_xor(sq, m);
    __syncthreads();
    if ((tid & 63) == 0) red[4 + (tid >> 6)] = sq;
    __syncthreads();
    float var = (red[4] + red[5] + red[6] + red[7]) * (1.0f / HID);
    float rs = rsqrtf(var + LNEPS);
    u16x4 o = { f2bf(d0*rs), f2bf(d1*rs), f2bf(d2*rs), f2bf(d3*rs) };
    *(u16x4*)(h_ext + (size_t)row * HID + tid * 4) = o;
  } else if (row < NROWS + RELN) {
    const float* src = rel + (size_t)(row - NROWS) * HID;
    f32x4 x = *(const f32x4*)(src + tid * 4);
    u16x4 o = { f2bf(x[0]), f2bf(x[1]), f2bf(x[2]), f2bf(x[3]) };
    *(u16x4*)(h_ext + (size_t)row * HID + tid * 4) = o;
  } else {
    u16x4 z = { 0, 0, 0, 0 };
    *(u16x4*)(h_ext + (size_t)row * HID + tid * 4) = z;
  }
}

// ---------------- NT GEMM: C[M,N] = A[M,K] * B[N,K]^T + bias, bf16 in, bf16/f32 out ------
// 128x128 tile, BK=64, global_load_lds(16B) with XOR-swizzled global source.
// 1D grid + XCD-chunked block swizzle (grid % 8 == 0).
template<int WRITE_F32>
__global__ __launch_bounds__(256) void k_gemm(const ushort* A, const ushort* Bw, const float* bias,
                                              ushort* Cb, float* Cf, int M, int N, int K) {
  __shared__ char smem[32768];
  char* As = smem;
  char* Bs = smem + 16384;
  int tid = threadIdx.x, lane = tid & 63, w = tid >> 6;
  int nbn = N >> 7;
  int per = gridDim.x >> 3;
  int gl = (blockIdx.x & 7) * per + (blockIdx.x >> 3);
  int bm = gl / nbn, bn = gl % nbn;
  int wr = w >> 1, wc = w & 1;
  int g = lane >> 4, r = lane & 15;
  f32x4 acc[4][4] = {};
  for (int ko = 0; ko < K; ko += 64) {
    __syncthreads();
    #pragma unroll
    for (int c = 0; c < 4; ++c) {
      int chunk = c * 256 + tid;
      int row = chunk >> 3;
      int kb = (chunk & 7) << 4;
      int kbs = kb ^ ((row & 7) << 4);   // pre-swizzled source column (bytes)
      const char* gA = (const char*)(A + (size_t)(bm * 128 + row) * K + ko) + kbs;
      const char* gB = (const char*)(Bw + (size_t)(bn * 128 + row) * K + ko) + kbs;
      __builtin_amdgcn_global_load_lds((const __attribute__((address_space(1))) void*)gA,
                                       (__attribute__((address_space(3))) void*)(As + c * 4096 + w * 1024),
                                       16, 0, 0);
      __builtin_amdgcn_global_load_lds((const __attribute__((address_space(1))) void*)gB,
                                       (__attribute__((address_space(3))) void*)(Bs + c * 4096 + w * 1024),
                                       16, 0, 0);
    }
    __syncthreads();
    #pragma unroll
    for (int kk = 0; kk < 2; ++kk) {
      s16x8 af[4], bf[4];
      #pragma unroll
      for (int mt = 0; mt < 4; ++mt) {
        int row = wr * 64 + mt * 16 + r;
        int kb = (kk * 64 + g * 16) ^ ((row & 7) << 4);
        af[mt] = *(const s16x8*)(As + row * 128 + kb);
      }
      #pragma unroll
      for (int nt = 0; nt < 4; ++nt) {
        int row = wc * 64 + nt * 16 + r;
        int kb = (kk * 64 + g * 16) ^ ((row & 7) << 4);
        bf[nt] = *(const s16x8*)(Bs + row * 128 + kb);
      }
      #pragma unroll
      for (int mt = 0; mt < 4; ++mt)
        #pragma unroll
        for (int nt = 0; nt < 4; ++nt)
          acc[mt][nt] = __builtin_amdgcn_mfma_f32_16x16x32_bf16(af[mt], bf[nt], acc[mt][nt], 0, 0, 0);
    }
  }
  #pragma unroll
  for (int nt = 0; nt < 4; ++nt) {
    int col = bn * 128 + wc * 64 + nt * 16 + r;
    float bvv = bias[col];
    #pragma unroll
    for (int mt = 0; mt < 4; ++mt) {
      int row0 = bm * 128 + wr * 64 + mt * 16 + g * 4;
      #pragma unroll
      for (int i = 0; i < 4; ++i) {
        float v = acc[mt][nt][i] + bvv;
        if (WRITE_F32) Cf[(size_t)(row0 + i) * N + col] = v;
        else           Cb[(size_t)(row0 + i) * N + col] = f2bf(v);
      }
    }
  }
}

// ---------------- positional score tables (bf16 out): qp[bh,q,t]=q.kpos[t] ---------------
__global__ __launch_bounds__(256) void k_pos(const ushort* qkv, ushort* qp, ushort* pk) {
  int bh = blockIdx.x;
  int b = bh >> 4, h = bh & 15;
  int tid = threadIdx.x, lane = tid & 63, w = tid >> 6;
  int g = lane >> 4, r = lane & 15;
  s16x8 bkp[4][2], bqp[4][2];   // kpos / qpos B-fragments (t = nt*16+r)
  #pragma unroll
  for (int nt = 0; nt < 4; ++nt)
    #pragma unroll
    for (int kk = 0; kk < 2; ++kk) {
      size_t rowp = (size_t)(NROWS + nt * 16 + r);
      int colq = h * 64 + kk * 32 + g * 8;
      bqp[nt][kk] = *(const s16x8*)(qkv + rowp * NQKV + colq);
      bkp[nt][kk] = *(const s16x8*)(qkv + rowp * NQKV + 1024 + colq);
    }
  for (int cc = 0; cc < 8; ++cc) {
    int rowbase = cc * 64 + w * 16;
    s16x8 aq[2], ak[2];
    #pragma unroll
    for (int kk = 0; kk < 2; ++kk) {
      size_t rowq = (size_t)((rowbase + r) * 16 + b);
      int colq = h * 64 + kk * 32 + g * 8;
      aq[kk] = *(const s16x8*)(qkv + rowq * NQKV + colq);
      ak[kk] = *(const s16x8*)(qkv + rowq * NQKV + 1024 + colq);
    }
    f32x4 accq[4] = {}, acck[4] = {};
    #pragma unroll
    for (int kk = 0; kk < 2; ++kk)
      #pragma unroll
      for (int nt = 0; nt < 4; ++nt) {
        accq[nt] = __builtin_amdgcn_mfma_f32_16x16x32_bf16(aq[kk], bkp[nt][kk], accq[nt], 0, 0, 0);
        acck[nt] = __builtin_amdgcn_mfma_f32_16x16x32_bf16(ak[kk], bqp[nt][kk], acck[nt], 0, 0, 0);
      }
    #pragma unroll
    for (int nt = 0; nt < 4; ++nt)
      #pragma unroll
      for (int i = 0; i < 4; ++i) {
        int q = rowbase + g * 4 + i;
        int t = nt * 16 + r;
        qp[(size_t)bh * SEQ * 64 + q * 64 + t] = f2bf(accq[nt][i]);
        pk[(size_t)bh * SEQ * 64 + q * 64 + t] = f2bf(acck[nt][i]);
      }
  }
}

// ---------------- V transpose: vt[b,h,d,l] <- qkv v-part ---------------------------------
__global__ __launch_bounds__(256) void k_vt(const ushort* qkv, ushort* vt) {
  int bid = blockIdx.x;
  int bh = bid >> 3, lt = bid & 7;
  int b = bh >> 4, h = bh & 15;
  __shared__ ushort tile[64][72];
  int tid = threadIdx.x;
  #pragma unroll
  for (int c = 0; c < 2; ++c) {
    int e = (c * 256 + tid) * 8;
    int l = e >> 6, d0 = e & 63;
    size_t row = (size_t)((lt * 64 + l) * 16 + b);
    *(s16x8*)&tile[l][d0] = *(const s16x8*)(qkv + row * NQKV + 2048 + h * 64 + d0);
  }
  __syncthreads();
  #pragma unroll
  for (int c = 0; c < 2; ++c) {
    int e = (c * 256 + tid) * 8;
    int d = e >> 6, l0 = e & 63;
    ushort tmp[8];
    #pragma unroll
    for (int j = 0; j < 8; ++j) tmp[j] = tile[l0 + j][d];
    *(s16x8*)(vt + (size_t)(bh * 64 + d) * SEQ + lt * 64 + l0) = *(s16x8*)tmp;
  }
}

// ---------------- fused attention: QK^T + bucket-gathered pos terms + softmax + PV -------
// XCD-aware block map (same-bh blocks share an XCD L2); pk/K prefetched; pipelined.
__global__ __launch_bounds__(256, 4) void k_attn(const ushort* qkv, const ushort* qp_all, const ushort* pk_all,
                                                 const ushort* vt, const float* maskbias, const int* idx_tab,
                                                 ushort* ctx) {
  int bid = blockIdx.x;
  int slot = bid >> 3;
  int bh = (bid & 7) * 32 + (slot >> 3);   // all 8 qt-blocks of a bh on one XCD
  int qt = slot & 7;
  int b = bh >> 4, h = bh & 15;
  int tid = threadIdx.x, lane = tid & 63, w = tid >> 6;
  int g = lane >> 4, r = lane & 15;

  __shared__ ushort qp_s[64][66];
  __shared__ ushort pk_s[64][66];
  __shared__ ushort p_s[4][16][68];
  __shared__ float  mb_s[512];
  __shared__ ushort idx_s[1024];

  const size_t qp_base = (size_t)bh * SEQ * 64 + (size_t)qt * 64 * 64;
  const size_t pk_base = (size_t)bh * SEQ * 64;

  // prologue global loads (issued first, consumed below)
  s16x8 pkreg[2], kreg[4][2], aq[2];
  #pragma unroll
  for (int c = 0; c < 2; ++c)
    pkreg[c] = *(const s16x8*)(pk_all + pk_base + (size_t)(c * 256 + tid) * 8);
  #pragma unroll
  for (int nt = 0; nt < 4; ++nt)
    #pragma unroll
    for (int kk = 0; kk < 2; ++kk) {
      size_t krow = (size_t)((nt * 16 + r) * 16 + b);
      kreg[nt][kk] = *(const s16x8*)(qkv + krow * NQKV + 1024 + h * 64 + kk * 32 + g * 8);
    }
  int qg0 = qt * 64 + w * 16;
  #pragma unroll
  for (int kk = 0; kk < 2; ++kk) {
    size_t row = (size_t)((qg0 + r) * 16 + b);
    aq[kk] = *(const s16x8*)(qkv + row * NQKV + h * 64 + kk * 32 + g * 8);
  }

  // stage qp tile (contiguous 8KB), mask bias, idx table
  #pragma unroll
  for (int c = 0; c < 2; ++c) {
    int chunk = c * 256 + tid;
    s16x8 v = *(const s16x8*)(qp_all + qp_base + (size_t)chunk * 8);
    *(s16x8*)&qp_s[chunk >> 3][(chunk & 7) * 8] = v;
  }
  for (int i = tid; i < 512; i += 256) mb_s[i] = maskbias[b * SEQ + i];
  for (int i = tid; i < 1023; i += 256) idx_s[i] = (ushort)idx_tab[i];
  // pk tile 0 -> LDS
  #pragma unroll
  for (int c = 0; c < 2; ++c) {
    int chunk = c * 256 + tid;
    *(s16x8*)&pk_s[chunk >> 3][(chunk & 7) * 8] = pkreg[c];
  }
  __syncthreads();
  // prefetch pk tile 1
  #pragma unroll
  for (int c = 0; c < 2; ++c)
    pkreg[c] = *(const s16x8*)(pk_all + pk_base + 4096 + (size_t)(c * 256 + tid) * 8);

  float m_i[4], l_i[4];
  f32x4 o_acc[4] = {};
  #pragma unroll
  for (int i = 0; i < 4; ++i) { m_i[i] = -3e38f; l_i[i] = 0.0f; }
  const float scale = 0.07216878364870323f;  // 1/sqrt(3*64)

  #pragma unroll
  for (int kt = 0; kt < 8; ++kt) {
    // QK^T on prefetched K fragments
    f32x4 s[4];
    #pragma unroll
    for (int nt = 0; nt < 4; ++nt) {
      f32x4 a = {};
      #pragma unroll
      for (int kk = 0; kk < 2; ++kk)
        a = __builtin_amdgcn_mfma_f32_16x16x32_bf16(aq[kk], kreg[nt][kk], a, 0, 0, 0);
      s[nt] = a;
    }
    // prefetch next K tile fragments
    s16x8 kn[4][2];
    if (kt < 7) {
      #pragma unroll
      for (int nt = 0; nt < 4; ++nt)
        #pragma unroll
        for (int kk = 0; kk < 2; ++kk) {
          size_t krow = (size_t)(((kt + 1) * 64 + nt * 16 + r) * 16 + b);
          kn[nt][kk] = *(const s16x8*)(qkv + krow * NQKV + 1024 + h * 64 + kk * 32 + g * 8);
        }
    }

    // softmax with bucket-gathered positional terms
    float p[4][4], tilemax[4];
    #pragma unroll
    for (int i = 0; i < 4; ++i) tilemax[i] = -3e38f;
    #pragma unroll
    for (int nt = 0; nt < 4; ++nt) {
      int kl = nt * 16 + r;
      int kgl = kt * 64 + kl;
      float mb = mb_s[kgl];
      #pragma unroll
      for (int i = 0; i < 4; ++i) {
        int ql = w * 16 + g * 4 + i;
        int ridx = (qt * 64 + ql) - kgl + 511;
        int t = idx_s[ridx];
        float v = (s[nt][i] + bf2f(qp_s[ql][t]) + bf2f(pk_s[kl][t])) * scale;
        v = (mb < 0.0f) ? -3e38f : v;
        s[nt][i] = v;
        tilemax[i] = fmaxf(tilemax[i], v);
      }
    }
    #pragma unroll
    for (int i = 0; i < 4; ++i) {
      float v = tilemax[i];
      v = fmaxf(v, __shfl_xor(v, 1));
      v = fmaxf(v, __shfl_xor(v, 2));
      v = fmaxf(v, __shfl_xor(v, 4));
      v = fmaxf(v, __shfl_xor(v, 8));
      tilemax[i] = v;
    }
    float rs_i[4], psum[4];
    #pragma unroll
    for (int i = 0; i < 4; ++i) {
      float mnew = fmaxf(m_i[i], tilemax[i]);
      rs_i[i] = __expf(m_i[i] - mnew);
      m_i[i] = mnew;
      l_i[i] *= rs_i[i];
      psum[i] = 0.0f;
    }
    #pragma unroll
    for (int nt = 0; nt < 4; ++nt)
      #pragma unroll
      for (int i = 0; i < 4; ++i) {
        float v = s[nt][i];
        float pe = (v <= -1e37f) ? 0.0f : __expf(v - m_i[i]);
        p[nt][i] = pe;
        psum[i] += pe;
      }
    #pragma unroll
    for (int i = 0; i < 4; ++i) {
      float v = psum[i];
      v += __shfl_xor(v, 1);
      v += __shfl_xor(v, 2);
      v += __shfl_xor(v, 4);
      v += __shfl_xor(v, 8);
      l_i[i] += v;
    }
    // issue V loads (overlap with o rescale + p_s roundtrip)
    s16x8 vreg[2][4];
    #pragma unroll
    for (int kk = 0; kk < 2; ++kk)
      #pragma unroll
      for (int nt = 0; nt < 4; ++nt)
        vreg[kk][nt] = *(const s16x8*)(vt + (size_t)(bh * 64 + nt * 16 + r) * SEQ + kt * 64 + kk * 32 + g * 8);

    #pragma unroll
    for (int nt = 0; nt < 4; ++nt)
      #pragma unroll
      for (int i = 0; i < 4; ++i) o_acc[nt][i] *= rs_i[i];

    #pragma unroll
    for (int nt = 0; nt < 4; ++nt)
      #pragma unroll
      for (int i = 0; i < 4; ++i) p_s[w][g * 4 + i][nt * 16 + r] = f2bf(p[nt][i]);

    #pragma unroll
    for (int kk = 0; kk < 2; ++kk) {
      s16x8 pa = *(const s16x8*)&p_s[w][r][kk * 32 + g * 8];
      #pragma unroll
      for (int nt = 0; nt < 4; ++nt)
        o_acc[nt] = __builtin_amdgcn_mfma_f32_16x16x32_bf16(pa, vreg[kk][nt], o_acc[nt], 0, 0, 0);
    }

    if (kt < 7) {
      __syncthreads();   // all waves done reading pk_s(kt)
      #pragma unroll
      for (int c = 0; c < 2; ++c) {
        int chunk = c * 256 + tid;
        *(s16x8*)&pk_s[chunk >> 3][(chunk & 7) * 8] = pkreg[c];
      }
      __syncthreads();   // pk_s(kt+1) visible
      if (kt < 6) {
        #pragma unroll
        for (int c = 0; c < 2; ++c)
          pkreg[c] = *(const s16x8*)(pk_all + pk_base + (size_t)(kt + 2) * 4096 + (size_t)(c * 256 + tid) * 8);
      }
      #pragma unroll
      for (int nt = 0; nt < 4; ++nt)
        #pragma unroll
        for (int kk = 0; kk < 2; ++kk) kreg[nt][kk] = kn[nt][kk];
    }
  }

  #pragma unroll
  for (int i = 0; i < 4; ++i) {
    float inv = l_i[i] > 0.0f ? 1.0f / l_i[i] : 0.0f;
    int lq = qt * 64 + w * 16 + g * 4 + i;
    size_t rowc = (size_t)(lq * 16 + b);
    #pragma unroll
    for (int nt = 0; nt < 4; ++nt)
      ctx[rowc * HID + h * 64 + nt * 16 + r] = f2bf(o_acc[nt][i] * inv);
  }
}

// ---------------- LN2 (affine) -> f32 out -------------------------------------------------
__global__ __launch_bounds__(256) void k_ln2(const float* tmp, const float* gamma, const float* beta,
                                             float* out) {
  int row = blockIdx.x, tid = threadIdx.x;
  __shared__ float red[8];
  const float* src = tmp + (size_t)row * HID;
  f32x4 x = *(const f32x4*)(src + tid * 4);
  float s = x[0] + x[1] + x[2] + x[3];
  #pragma unroll
  for (int m = 1; m < 64; m <<= 1) s += __shfl_xor(s, m);
  if ((tid & 63) == 0) red[tid >> 6] = s;
  __syncthreads();
  float mean = (red[0] + red[1] + red[2] + red[3]) * (1.0f / HID);
  float d[4]; float sq = 0.0f;
  #pragma unroll
  for (int j = 0; j < 4; ++j) { d[j] = x[j] - mean; sq += d[j] * d[j]; }
  #pragma unroll
  for (int m = 1; m < 64; m <<= 1) sq += __shfl_xor(sq, m);
  __syncthreads();
  if ((tid & 63) == 0) red[4 + (tid >> 6)] = sq;
  __syncthreads();
  float var = (red[4] + red[5] + red[6] + red[7]) * (1.0f / HID);
  float rs = rsqrtf(var + LNEPS);
  f32x4 o;
  #pragma unroll
  for (int j = 0; j < 4; ++j) o[j] = d[j] * rs * gamma[tid * 4 + j] + beta[tid * 4 + j];
  *(f32x4*)(out + (size_t)row * HID + tid * 4) = o;
}

// ---------------- launch -----------------------------------------------------------------
extern "C" void kernel_launch(void* const* d_in, const int* in_sizes, int n_in,
                              void* d_out, int out_size, void* d_ws, size_t ws_size,
                              hipStream_t stream) {
  (void)in_sizes; (void)n_in; (void)out_size; (void)ws_size;
  const float* hid  = (const float*)d_in[0];
  const void*  mask = d_in[1];
  const float* rel  = (const float*)d_in[2];
  const float* wqk  = (const float*)d_in[3];
  const float* bqk  = (const float*)d_in[4];
  const float* wv   = (const float*)d_in[5];
  const float* bv   = (const float*)d_in[6];
  const float* wo   = (const float*)d_in[7];
  const float* bo   = (const float*)d_in[8];
  const float* ln_g = (const float*)d_in[9];
  const float* ln_b = (const float*)d_in[10];

  char* ws = (char*)d_ws;
  ushort* wcat     = (ushort*)(ws);                 //  6,291,456
  ushort* wo_b     = (ushort*)(ws + 6291456);       //  2,097,152
  float*  bcat     = (float*) (ws + 8388608);       //     12,288
  float*  maskbias = (float*) (ws + 8400896);       //     32,768
  int*    idx_tab  = (int*)   (ws + 8433664);       //      4,096
  ushort* h_ext    = (ushort*)(ws + 8437760);       // 17,039,360  (reused as ctx)
  ushort* qkv      = (ushort*)(ws + 25477120);      // 51,118,080
  ushort* qp_b     = (ushort*)(ws + 76595200);      // 16,777,216 (bf16 now)
  ushort* pk_b     = (ushort*)(ws + 93372416);      // 16,777,216
  ushort* vt       = (ushort*)(ws + 110149632);     // 16,777,216
  float*  tmp      = (float*) (ws + 126926848);     // 33,554,432  -> total 160,481,280
  ushort* ctx = h_ext;

  k_prep<<<1, 256, 0, stream>>>(mask, bqk, bv, maskbias, idx_tab, bcat);
  k_convert<<<12288, 256, 0, stream>>>(wqk, wv, wo, wcat, wo_b);
  k_ln1<<<MEXT, 256, 0, stream>>>(hid, rel, h_ext);
  k_gemm<0><<<(MEXT / 128) * (NQKV / 128), 256, 0, stream>>>(h_ext, wcat, bcat, qkv, nullptr, MEXT, NQKV, 1024);
  k_pos<<<256, 256, 0, stream>>>(qkv, qp_b, pk_b);
  k_vt<<<2048, 256, 0, stream>>>(qkv, vt);
  k_attn<<<2048, 256, 0, stream>>>(qkv, qp_b, pk_b, vt, maskbias, idx_tab, ctx);
  k_gemm<1><<<(NROWS / 128) * (1024 / 128), 256, 0, stream>>>(ctx, wo_b, bo, nullptr, tmp, NROWS, 1024, 1024);
  k_ln2<<<NROWS, 256, 0, stream>>>(tmp, ln_g, ln_b, (float*)d_out);
}

// Round 3
// 290.815 us; speedup vs baseline: 1.9028x; 1.9028x over previous
//
#include <hip/hip_runtime.h>
#include <hip/hip_bf16.h>

#define HID 1024
#define HEADS 16
#define HEAD 64
#define RELN 63
#define SEQ 512
#define BATCH 16
#define NROWS (SEQ*BATCH)      // 8192
#define MEXT 8320              // 8192 + 63, padded to 65*128
#define NQKV 3072
#define LNEPS 1e-7f

typedef __attribute__((ext_vector_type(4))) float  f32x4;
typedef __attribute__((ext_vector_type(8))) short  s16x8;
typedef __attribute__((ext_vector_type(4))) ushort u16x4;

static __device__ __forceinline__ ushort f2bf(float f) {
  union { float f; unsigned u; } v; v.f = f;
  unsigned r = v.u + 0x7fffu + ((v.u >> 16) & 1u);
  return (ushort)(r >> 16);
}
static __device__ __forceinline__ float bf2f(ushort u) {
  union { unsigned u; float f; } v; v.u = ((unsigned)u) << 16;
  return v.f;
}

// ---------------- prep: mask dtype detect + mask01 + bucket idx table + bias concat ------
__global__ void k_prep(const void* mask_raw, const float* bqk, const float* bv,
                       ushort* mask01, int* idx_tab, float* bcat) {
  __shared__ int s_isbool;
  int tid = threadIdx.x;
  if (tid == 0) s_isbool = 0;
  __syncthreads();
  const unsigned* mu = (const unsigned*)mask_raw;
  int bad = 0;
  for (int i = tid; i < 2048; i += 256) if (mu[i] > 1u) bad = 1;
  if (bad) s_isbool = 1;              // benign race: any writer writes 1
  __syncthreads();
  int isbool = s_isbool;
  const unsigned char* m8 = (const unsigned char*)mask_raw;
  const int* m32 = (const int*)mask_raw;
  for (int i = tid; i < BATCH*SEQ; i += 256) {
    int m = isbool ? (int)m8[i] : m32[i];
    mask01[i] = m ? 1 : 0;
  }
  for (int i = tid; i < 1023; i += 256) {
    int r = i - 511;
    int a = r < 0 ? -r : r;
    int absp = (a < 16) ? 15 : (a < 511 ? a : 511);
    int idx;
    if (absp <= 16) idx = 31 + r;
    else {
      float v = logf((float)absp / 16.0f) / logf(511.0f / 16.0f) * 15.0f;
      int lp = (int)ceilf(v) + 16;
      idx = 31 + (r > 0 ? lp : -lp);
    }
    idx_tab[i] = idx;
  }
  for (int i = tid; i < 2048; i += 256) bcat[i] = bqk[i];
  for (int i = tid; i < 1024; i += 256) bcat[2048 + i] = bv[i];
}

// ---------------- f32 -> bf16 weight conversion (wqk|wv concat, wo) ----------------------
__global__ void k_convert(const float* wqk, const float* wv, const float* wo,
                          ushort* wcat, ushort* wo_b) {
  int i = blockIdx.x * 256 + threadIdx.x;
  if (i < 2048 * 1024) wcat[i] = f2bf(wqk[i]);
  else if (i < 3072 * 1024) wcat[i] = f2bf(wv[i - 2048 * 1024]);
  if (i < 1024 * 1024) wo_b[i] = f2bf(wo[i]);
}

// ---------------- LN1 (no affine) -> bf16, plus rel-embedding rows + zero pad ------------
__global__ __launch_bounds__(256) void k_ln1(const float* hid, const float* rel, ushort* h_ext) {
  int row = blockIdx.x, tid = threadIdx.x;
  __shared__ float red[8];
  if (row < NROWS) {
    const float* src = hid + (size_t)row * HID;
    f32x4 x = *(const f32x4*)(src + tid * 4);
    float s = x[0] + x[1] + x[2] + x[3];
    #pragma unroll
    for (int m = 1; m < 64; m <<= 1) s += __shfl_xor(s, m);
    if ((tid & 63) == 0) red[tid >> 6] = s;
    __syncthreads();
    float mean = (red[0] + red[1] + red[2] + red[3]) * (1.0f / HID);
    float d0 = x[0] - mean, d1 = x[1] - mean, d2 = x[2] - mean, d3 = x[3] - mean;
    float sq = d0*d0 + d1*d1 + d2*d2 + d3*d3;
    #pragma unroll
    for (int m = 1; m < 64; m <<= 1) sq += __shfl_xor(sq, m);
    __syncthreads();
    if ((tid & 63) == 0) red[4 + (tid >> 6)] = sq;
    __syncthreads();
    float var = (red[4] + red[5] + red[6] + red[7]) * (1.0f / HID);
    float rs = rsqrtf(var + LNEPS);
    u16x4 o = { f2bf(d0*rs), f2bf(d1*rs), f2bf(d2*rs), f2bf(d3*rs) };
    *(u16x4*)(h_ext + (size_t)row * HID + tid * 4) = o;
  } else if (row < NROWS + RELN) {
    const float* src = rel + (size_t)(row - NROWS) * HID;
    f32x4 x = *(const f32x4*)(src + tid * 4);
    u16x4 o = { f2bf(x[0]), f2bf(x[1]), f2bf(x[2]), f2bf(x[3]) };
    *(u16x4*)(h_ext + (size_t)row * HID + tid * 4) = o;
  } else {
    u16x4 z = { 0, 0, 0, 0 };
    *(u16x4*)(h_ext + (size_t)row * HID + tid * 4) = z;
  }
}

// ---------------- NT GEMM: C[M,N] = A[M,K] * B[N,K]^T + bias, bf16 in, bf16/f32 out ------
// 128x128 tile, BK=64, global_load_lds(16B) with XOR-swizzled global source.
// 1D grid + XCD-chunked block swizzle (grid % 8 == 0).
template<int WRITE_F32>
__global__ __launch_bounds__(256) void k_gemm(const ushort* A, const ushort* Bw, const float* bias,
                                              ushort* Cb, float* Cf, int M, int N, int K) {
  __shared__ char smem[32768];
  char* As = smem;
  char* Bs = smem + 16384;
  int tid = threadIdx.x, lane = tid & 63, w = tid >> 6;
  int nbn = N >> 7;
  int per = gridDim.x >> 3;
  int gl = (blockIdx.x & 7) * per + (blockIdx.x >> 3);
  int bm = gl / nbn, bn = gl % nbn;
  int wr = w >> 1, wc = w & 1;
  int g = lane >> 4, r = lane & 15;
  f32x4 acc[4][4] = {};
  for (int ko = 0; ko < K; ko += 64) {
    __syncthreads();
    #pragma unroll
    for (int c = 0; c < 4; ++c) {
      int chunk = c * 256 + tid;
      int row = chunk >> 3;
      int kb = (chunk & 7) << 4;
      int kbs = kb ^ ((row & 7) << 4);   // pre-swizzled source column (bytes)
      const char* gA = (const char*)(A + (size_t)(bm * 128 + row) * K + ko) + kbs;
      const char* gB = (const char*)(Bw + (size_t)(bn * 128 + row) * K + ko) + kbs;
      __builtin_amdgcn_global_load_lds((const __attribute__((address_space(1))) void*)gA,
                                       (__attribute__((address_space(3))) void*)(As + c * 4096 + w * 1024),
                                       16, 0, 0);
      __builtin_amdgcn_global_load_lds((const __attribute__((address_space(1))) void*)gB,
                                       (__attribute__((address_space(3))) void*)(Bs + c * 4096 + w * 1024),
                                       16, 0, 0);
    }
    __syncthreads();
    #pragma unroll
    for (int kk = 0; kk < 2; ++kk) {
      s16x8 af[4], bf[4];
      #pragma unroll
      for (int mt = 0; mt < 4; ++mt) {
        int row = wr * 64 + mt * 16 + r;
        int kb = (kk * 64 + g * 16) ^ ((row & 7) << 4);
        af[mt] = *(const s16x8*)(As + row * 128 + kb);
      }
      #pragma unroll
      for (int nt = 0; nt < 4; ++nt) {
        int row = wc * 64 + nt * 16 + r;
        int kb = (kk * 64 + g * 16) ^ ((row & 7) << 4);
        bf[nt] = *(const s16x8*)(Bs + row * 128 + kb);
      }
      #pragma unroll
      for (int mt = 0; mt < 4; ++mt)
        #pragma unroll
        for (int nt = 0; nt < 4; ++nt)
          acc[mt][nt] = __builtin_amdgcn_mfma_f32_16x16x32_bf16(af[mt], bf[nt], acc[mt][nt], 0, 0, 0);
    }
  }
  #pragma unroll
  for (int nt = 0; nt < 4; ++nt) {
    int col = bn * 128 + wc * 64 + nt * 16 + r;
    float bvv = bias[col];
    #pragma unroll
    for (int mt = 0; mt < 4; ++mt) {
      int row0 = bm * 128 + wr * 64 + mt * 16 + g * 4;
      #pragma unroll
      for (int i = 0; i < 4; ++i) {
        float v = acc[mt][nt][i] + bvv;
        if (WRITE_F32) Cf[(size_t)(row0 + i) * N + col] = v;
        else           Cb[(size_t)(row0 + i) * N + col] = f2bf(v);
      }
    }
  }
}

// ---------------- positional score tables (bf16 out): qp[bh,q,t]=q.kpos[t] ---------------
__global__ __launch_bounds__(256) void k_pos(const ushort* qkv, ushort* qp, ushort* pk) {
  int bh = blockIdx.x;
  int b = bh >> 4, h = bh & 15;
  int tid = threadIdx.x, lane = tid & 63, w = tid >> 6;
  int g = lane >> 4, r = lane & 15;
  s16x8 bkp[4][2], bqp[4][2];   // kpos / qpos B-fragments (t = nt*16+r)
  #pragma unroll
  for (int nt = 0; nt < 4; ++nt)
    #pragma unroll
    for (int kk = 0; kk < 2; ++kk) {
      size_t rowp = (size_t)(NROWS + nt * 16 + r);
      int colq = h * 64 + kk * 32 + g * 8;
      bqp[nt][kk] = *(const s16x8*)(qkv + rowp * NQKV + colq);
      bkp[nt][kk] = *(const s16x8*)(qkv + rowp * NQKV + 1024 + colq);
    }
  for (int cc = 0; cc < 8; ++cc) {
    int rowbase = cc * 64 + w * 16;
    s16x8 aq[2], ak[2];
    #pragma unroll
    for (int kk = 0; kk < 2; ++kk) {
      size_t rowq = (size_t)((rowbase + r) * 16 + b);
      int colq = h * 64 + kk * 32 + g * 8;
      aq[kk] = *(const s16x8*)(qkv + rowq * NQKV + colq);
      ak[kk] = *(const s16x8*)(qkv + rowq * NQKV + 1024 + colq);
    }
    f32x4 accq[4] = {}, acck[4] = {};
    #pragma unroll
    for (int kk = 0; kk < 2; ++kk)
      #pragma unroll
      for (int nt = 0; nt < 4; ++nt) {
        accq[nt] = __builtin_amdgcn_mfma_f32_16x16x32_bf16(aq[kk], bkp[nt][kk], accq[nt], 0, 0, 0);
        acck[nt] = __builtin_amdgcn_mfma_f32_16x16x32_bf16(ak[kk], bqp[nt][kk], acck[nt], 0, 0, 0);
      }
    #pragma unroll
    for (int nt = 0; nt < 4; ++nt)
      #pragma unroll
      for (int i = 0; i < 4; ++i) {
        int q = rowbase + g * 4 + i;
        int t = nt * 16 + r;
        qp[(size_t)bh * SEQ * 64 + q * 64 + t] = f2bf(accq[nt][i]);
        pk[(size_t)bh * SEQ * 64 + q * 64 + t] = f2bf(acck[nt][i]);
      }
  }
}

// ---------------- V transpose + K repack: vt[b,h,d,l], kc[b,h,l,d] -----------------------
__global__ __launch_bounds__(256) void k_vt(const ushort* qkv, ushort* vt, ushort* kc) {
  int bid = blockIdx.x;
  int bh = bid >> 3, lt = bid & 7;
  int b = bh >> 4, h = bh & 15;
  __shared__ ushort tile[64][72];
  int tid = threadIdx.x;
  #pragma unroll
  for (int c = 0; c < 2; ++c) {
    int e = (c * 256 + tid) * 8;
    int l = e >> 6, d0 = e & 63;
    size_t row = (size_t)((lt * 64 + l) * 16 + b);
    s16x8 kv = *(const s16x8*)(qkv + row * NQKV + 1024 + h * 64 + d0);
    *(s16x8*)(kc + ((size_t)bh * SEQ + lt * 64 + l) * 64 + d0) = kv;   // contiguous K rows
    *(s16x8*)&tile[l][d0] = *(const s16x8*)(qkv + row * NQKV + 2048 + h * 64 + d0);
  }
  __syncthreads();
  #pragma unroll
  for (int c = 0; c < 2; ++c) {
    int e = (c * 256 + tid) * 8;
    int d = e >> 6, l0 = e & 63;
    ushort tmp[8];
    #pragma unroll
    for (int j = 0; j < 8; ++j) tmp[j] = tile[l0 + j][d];
    *(s16x8*)(vt + (size_t)(bh * 64 + d) * SEQ + lt * 64 + l0) = *(s16x8*)tmp;
  }
}

// ---------------- fused attention -------------------------------------------------------
// XCD-aware block map; K via global_load_lds double-buffer (swizzled), pk double-buffered
// via 8-VGPR reg split; V issued early; ONE barrier per kt iteration. No occupancy cap.
__global__ __launch_bounds__(256) void k_attn(const ushort* qkv, const ushort* qp_all, const ushort* pk_all,
                                              const ushort* kc, const ushort* vt, const ushort* mask01,
                                              const int* idx_tab, ushort* ctx) {
  int bid = blockIdx.x;
  int slot = bid >> 3;
  int bh = (bid & 7) * 32 + (slot >> 3);   // all 8 qt-blocks of a bh on one XCD
  int qt = slot & 7;
  int b = bh >> 4, h = bh & 15;
  int tid = threadIdx.x, lane = tid & 63, w = tid >> 6;
  int g = lane >> 4, r = lane & 15;

  __shared__ ushort qp_s[64][66];
  __shared__ ushort pk_s[2][64][66];
  __shared__ char   Ks[2][8192];
  __shared__ ushort p_s[4][16][72];
  __shared__ ushort mb_s[512];
  __shared__ ushort idx_s[1024];
  char* Ksp = (char*)Ks;

  const size_t qp_base = (size_t)bh * SEQ * 64 + (size_t)qt * 4096;
  const size_t pk_base = (size_t)bh * SEQ * 64;
  const char* kcb = (const char*)(kc + (size_t)bh * SEQ * 64);   // [l][d] 128B rows

  int krow = w * 8 + (lane >> 3);                       // staging row (+c*32)
  int ksrccol = (((lane & 7) ^ (lane >> 3)) << 4);      // pre-swizzled source col (bytes)

  // ---- prologue: stage K(0), pk(0), qp, mb, idx, aq ----
  #pragma unroll
  for (int c = 0; c < 2; ++c) {
    const char* src = kcb + (size_t)(c * 32 + krow) * 128 + ksrccol;
    __builtin_amdgcn_global_load_lds((const __attribute__((address_space(1))) void*)src,
                                     (__attribute__((address_space(3))) void*)(Ksp + c * 4096 + w * 1024),
                                     16, 0, 0);
  }
  s16x8 pkreg[2];
  #pragma unroll
  for (int c = 0; c < 2; ++c)
    pkreg[c] = *(const s16x8*)(pk_all + pk_base + (size_t)(c * 256 + tid) * 8);
  #pragma unroll
  for (int c = 0; c < 2; ++c) {
    int chunk = c * 256 + tid;
    s16x8 v = *(const s16x8*)(qp_all + qp_base + (size_t)chunk * 8);
    *(s16x8*)&qp_s[chunk >> 3][(chunk & 7) * 8] = v;
  }
  for (int i = tid; i < 512; i += 256) mb_s[i] = mask01[b * SEQ + i];
  for (int i = tid; i < 1023; i += 256) idx_s[i] = (ushort)idx_tab[i];
  s16x8 aq[2];
  int qg0 = qt * 64 + w * 16;
  #pragma unroll
  for (int kk = 0; kk < 2; ++kk) {
    size_t row = (size_t)((qg0 + r) * 16 + b);
    aq[kk] = *(const s16x8*)(qkv + row * NQKV + h * 64 + kk * 32 + g * 8);
  }
  #pragma unroll
  for (int c = 0; c < 2; ++c) {
    int chunk = c * 256 + tid;
    *(s16x8*)&pk_s[0][chunk >> 3][(chunk & 7) * 8] = pkreg[c];
  }
  __syncthreads();   // drains K(0) vmcnt too

  float m_i[4], l_i[4];
  f32x4 o_acc[4] = {};
  #pragma unroll
  for (int i = 0; i < 4; ++i) { m_i[i] = -3e38f; l_i[i] = 0.0f; }
  const float scale = 0.07216878364870323f;  // 1/sqrt(3*64)

  #pragma unroll 2
  for (int kt = 0; kt < 8; ++kt) {
    const int cur = kt & 1;
    // ---- issue next-tile staging (lands at end-of-iteration barrier) ----
    if (kt < 7) {
      #pragma unroll
      for (int c = 0; c < 2; ++c) {
        const char* src = kcb + (size_t)(kt + 1) * 8192 + (size_t)(c * 32 + krow) * 128 + ksrccol;
        __builtin_amdgcn_global_load_lds((const __attribute__((address_space(1))) void*)src,
                                         (__attribute__((address_space(3))) void*)(Ksp + (cur ^ 1) * 8192 + c * 4096 + w * 1024),
                                         16, 0, 0);
      }
      #pragma unroll
      for (int c = 0; c < 2; ++c)
        pkreg[c] = *(const s16x8*)(pk_all + pk_base + (size_t)(kt + 1) * 4096 + (size_t)(c * 256 + tid) * 8);
    }

    // ---- QK^T from swizzled LDS K ----
    const char* Kc = Ksp + cur * 8192;
    f32x4 s[4];
    #pragma unroll
    for (int nt = 0; nt < 4; ++nt) {
      f32x4 a = {};
      #pragma unroll
      for (int kk = 0; kk < 2; ++kk) {
        s16x8 bk = *(const s16x8*)(Kc + (nt * 16 + r) * 128 + ((kk * 64 + g * 16) ^ ((r & 7) << 4)));
        a = __builtin_amdgcn_mfma_f32_16x16x32_bf16(aq[kk], bk, a, 0, 0, 0);
      }
      s[nt] = a;
    }

    // ---- issue V loads early (softmax covers their latency) ----
    s16x8 vreg[2][4];
    #pragma unroll
    for (int kk = 0; kk < 2; ++kk)
      #pragma unroll
      for (int nt = 0; nt < 4; ++nt)
        vreg[kk][nt] = *(const s16x8*)(vt + (size_t)(bh * 64 + nt * 16 + r) * SEQ + kt * 64 + kk * 32 + g * 8);

    // ---- softmax with bucket-gathered positional terms ----
    float p[4][4], tilemax[4];
    #pragma unroll
    for (int i = 0; i < 4; ++i) tilemax[i] = -3e38f;
    #pragma unroll
    for (int nt = 0; nt < 4; ++nt) {
      int kl = nt * 16 + r;
      int kgl = kt * 64 + kl;
      ushort mb = mb_s[kgl];
      #pragma unroll
      for (int i = 0; i < 4; ++i) {
        int ql = w * 16 + g * 4 + i;
        int ridx = (qt * 64 + ql) - kgl + 511;
        int t = idx_s[ridx];
        float v = (s[nt][i] + bf2f(qp_s[ql][t]) + bf2f(pk_s[cur][kl][t])) * scale;
        v = mb ? -3e38f : v;
        s[nt][i] = v;
        tilemax[i] = fmaxf(tilemax[i], v);
      }
    }
    #pragma unroll
    for (int i = 0; i < 4; ++i) {
      float v = tilemax[i];
      v = fmaxf(v, __shfl_xor(v, 1));
      v = fmaxf(v, __shfl_xor(v, 2));
      v = fmaxf(v, __shfl_xor(v, 4));
      v = fmaxf(v, __shfl_xor(v, 8));
      tilemax[i] = v;
    }
    float rs_i[4], psum[4];
    #pragma unroll
    for (int i = 0; i < 4; ++i) {
      float mnew = fmaxf(m_i[i], tilemax[i]);
      rs_i[i] = __expf(m_i[i] - mnew);
      m_i[i] = mnew;
      l_i[i] *= rs_i[i];
      psum[i] = 0.0f;
    }
    #pragma unroll
    for (int nt = 0; nt < 4; ++nt)
      #pragma unroll
      for (int i = 0; i < 4; ++i) {
        float v = s[nt][i];
        float pe = (v <= -1e37f) ? 0.0f : __expf(v - m_i[i]);
        p[nt][i] = pe;
        psum[i] += pe;
      }
    #pragma unroll
    for (int i = 0; i < 4; ++i) {
      float v = psum[i];
      v += __shfl_xor(v, 1);
      v += __shfl_xor(v, 2);
      v += __shfl_xor(v, 4);
      v += __shfl_xor(v, 8);
      l_i[i] += v;
    }
    #pragma unroll
    for (int nt = 0; nt < 4; ++nt)
      #pragma unroll
      for (int i = 0; i < 4; ++i) o_acc[nt][i] *= rs_i[i];

    // ---- P -> bf16 via per-wave LDS roundtrip, then PV ----
    #pragma unroll
    for (int nt = 0; nt < 4; ++nt)
      #pragma unroll
      for (int i = 0; i < 4; ++i) p_s[w][g * 4 + i][nt * 16 + r] = f2bf(p[nt][i]);

    #pragma unroll
    for (int kk = 0; kk < 2; ++kk) {
      s16x8 pa = *(const s16x8*)&p_s[w][r][kk * 32 + g * 8];
      #pragma unroll
      for (int nt = 0; nt < 4; ++nt)
        o_acc[nt] = __builtin_amdgcn_mfma_f32_16x16x32_bf16(pa, vreg[kk][nt], o_acc[nt], 0, 0, 0);
    }

    // ---- write pk(kt+1) into the other buffer, single barrier ----
    if (kt < 7) {
      #pragma unroll
      for (int c = 0; c < 2; ++c) {
        int chunk = c * 256 + tid;
        *(s16x8*)&pk_s[cur ^ 1][chunk >> 3][(chunk & 7) * 8] = pkreg[c];
      }
    }
    __syncthreads();
  }

  #pragma unroll
  for (int i = 0; i < 4; ++i) {
    float inv = l_i[i] > 0.0f ? 1.0f / l_i[i] : 0.0f;
    int lq = qt * 64 + w * 16 + g * 4 + i;
    size_t rowc = (size_t)(lq * 16 + b);
    #pragma unroll
    for (int nt = 0; nt < 4; ++nt)
      ctx[rowc * HID + h * 64 + nt * 16 + r] = f2bf(o_acc[nt][i] * inv);
  }
}

// ---------------- LN2 (affine) -> f32 out -------------------------------------------------
__global__ __launch_bounds__(256) void k_ln2(const float* tmp, const float* gamma, const float* beta,
                                             float* out) {
  int row = blockIdx.x, tid = threadIdx.x;
  __shared__ float red[8];
  const float* src = tmp + (size_t)row * HID;
  f32x4 x = *(const f32x4*)(src + tid * 4);
  float s = x[0] + x[1] + x[2] + x[3];
  #pragma unroll
  for (int m = 1; m < 64; m <<= 1) s += __shfl_xor(s, m);
  if ((tid & 63) == 0) red[tid >> 6] = s;
  __syncthreads();
  float mean = (red[0] + red[1] + red[2] + red[3]) * (1.0f / HID);
  float d[4]; float sq = 0.0f;
  #pragma unroll
  for (int j = 0; j < 4; ++j) { d[j] = x[j] - mean; sq += d[j] * d[j]; }
  #pragma unroll
  for (int m = 1; m < 64; m <<= 1) sq += __shfl_xor(sq, m);
  __syncthreads();
  if ((tid & 63) == 0) red[4 + (tid >> 6)] = sq;
  __syncthreads();
  float var = (red[4] + red[5] + red[6] + red[7]) * (1.0f / HID);
  float rs = rsqrtf(var + LNEPS);
  f32x4 o;
  #pragma unroll
  for (int j = 0; j < 4; ++j) o[j] = d[j] * rs * gamma[tid * 4 + j] + beta[tid * 4 + j];
  *(f32x4*)(out + (size_t)row * HID + tid * 4) = o;
}

// ---------------- launch -----------------------------------------------------------------
extern "C" void kernel_launch(void* const* d_in, const int* in_sizes, int n_in,
                              void* d_out, int out_size, void* d_ws, size_t ws_size,
                              hipStream_t stream) {
  (void)in_sizes; (void)n_in; (void)out_size; (void)ws_size;
  const float* hid  = (const float*)d_in[0];
  const void*  mask = d_in[1];
  const float* rel  = (const float*)d_in[2];
  const float* wqk  = (const float*)d_in[3];
  const float* bqk  = (const float*)d_in[4];
  const float* wv   = (const float*)d_in[5];
  const float* bv   = (const float*)d_in[6];
  const float* wo   = (const float*)d_in[7];
  const float* bo   = (const float*)d_in[8];
  const float* ln_g = (const float*)d_in[9];
  const float* ln_b = (const float*)d_in[10];

  char* ws = (char*)d_ws;
  ushort* wcat     = (ushort*)(ws);                 //  6,291,456
  ushort* wo_b     = (ushort*)(ws + 6291456);       //  2,097,152
  float*  bcat     = (float*) (ws + 8388608);       //     12,288
  ushort* mask01   = (ushort*)(ws + 8400896);       //     16,384 (region 32,768)
  int*    idx_tab  = (int*)   (ws + 8433664);       //      4,096
  ushort* h_ext    = (ushort*)(ws + 8437760);       // 17,039,360  (reused as ctx)
  ushort* qkv      = (ushort*)(ws + 25477120);      // 51,118,080
  ushort* qp_b     = (ushort*)(ws + 76595200);      // 16,777,216 (bf16)
  ushort* pk_b     = (ushort*)(ws + 93372416);      // 16,777,216
  ushort* vt       = (ushort*)(ws + 110149632);     // 16,777,216
  float*  tmp      = (float*) (ws + 126926848);     // 33,554,432  -> total 160,481,280
  ushort* ctx = h_ext;
  ushort* kc  = (ushort*)tmp;   // kc[bh][l][d] 16.7MB lives in tmp (dead until gemm<1>)

  k_prep<<<1, 256, 0, stream>>>(mask, bqk, bv, mask01, idx_tab, bcat);
  k_convert<<<12288, 256, 0, stream>>>(wqk, wv, wo, wcat, wo_b);
  k_ln1<<<MEXT, 256, 0, stream>>>(hid, rel, h_ext);
  k_gemm<0><<<(MEXT / 128) * (NQKV / 128), 256, 0, stream>>>(h_ext, wcat, bcat, qkv, nullptr, MEXT, NQKV, 1024);
  k_pos<<<256, 256, 0, stream>>>(qkv, qp_b, pk_b);
  k_vt<<<2048, 256, 0, stream>>>(qkv, vt, kc);
  k_attn<<<2048, 256, 0, stream>>>(qkv, qp_b, pk_b, kc, vt, mask01, idx_tab, ctx);
  k_gemm<1><<<(NROWS / 128) * (1024 / 128), 256, 0, stream>>>(ctx, wo_b, bo, nullptr, tmp, NROWS, 1024, 1024);
  k_ln2<<<NROWS, 256, 0, stream>>>(tmp, ln_g, ln_b, (float*)d_out);
}

// Round 4
// 266.938 us; speedup vs baseline: 2.0730x; 1.0894x over previous
//
#include <hip/hip_runtime.h>
#include <hip/hip_bf16.h>

#define HID 1024
#define HEADS 16
#define HEAD 64
#define RELN 63
#define SEQ 512
#define BATCH 16
#define NROWS (SEQ*BATCH)      // 8192
#define MEXT 8320              // 8192 + 63, padded to 65*128
#define NQKV 3072
#define LNEPS 1e-7f
#define SCALEF 0.07216878364870323f   // 1/sqrt(3*64), folded into kc + pos tables

typedef __attribute__((ext_vector_type(4))) float  f32x4;
typedef __attribute__((ext_vector_type(8))) short  s16x8;
typedef __attribute__((ext_vector_type(4))) ushort u16x4;

static __device__ __forceinline__ ushort f2bf(float f) {
  union { float f; unsigned u; } v; v.f = f;
  unsigned r = v.u + 0x7fffu + ((v.u >> 16) & 1u);
  return (ushort)(r >> 16);
}
static __device__ __forceinline__ float bf2f(ushort u) {
  union { unsigned u; float f; } v; v.u = ((unsigned)u) << 16;
  return v.f;
}

// ---------------- prep: mask dtype detect + mask01 + bucket idx table + bias concat ------
__global__ void k_prep(const void* mask_raw, const float* bqk, const float* bv,
                       ushort* mask01, int* idx_tab, float* bcat) {
  __shared__ int s_isbool;
  int tid = threadIdx.x;
  if (tid == 0) s_isbool = 0;
  __syncthreads();
  const unsigned* mu = (const unsigned*)mask_raw;
  int bad = 0;
  for (int i = tid; i < 2048; i += 256) if (mu[i] > 1u) bad = 1;
  if (bad) s_isbool = 1;              // benign race: any writer writes 1
  __syncthreads();
  int isbool = s_isbool;
  const unsigned char* m8 = (const unsigned char*)mask_raw;
  const int* m32 = (const int*)mask_raw;
  for (int i = tid; i < BATCH*SEQ; i += 256) {
    int m = isbool ? (int)m8[i] : m32[i];
    mask01[i] = m ? 1 : 0;
  }
  for (int i = tid; i < 1023; i += 256) {
    int r = i - 511;
    int a = r < 0 ? -r : r;
    int absp = (a < 16) ? 15 : (a < 511 ? a : 511);
    int idx;
    if (absp <= 16) idx = 31 + r;
    else {
      float v = logf((float)absp / 16.0f) / logf(511.0f / 16.0f) * 15.0f;
      int lp = (int)ceilf(v) + 16;
      idx = 31 + (r > 0 ? lp : -lp);
    }
    idx_tab[i] = idx;
  }
  for (int i = tid; i < 2048; i += 256) bcat[i] = bqk[i];
  for (int i = tid; i < 1024; i += 256) bcat[2048 + i] = bv[i];
}

// ---------------- f32 -> bf16 weight conversion (wqk|wv concat, wo) ----------------------
__global__ void k_convert(const float* wqk, const float* wv, const float* wo,
                          ushort* wcat, ushort* wo_b) {
  int i = blockIdx.x * 256 + threadIdx.x;
  if (i < 2048 * 1024) wcat[i] = f2bf(wqk[i]);
  else if (i < 3072 * 1024) wcat[i] = f2bf(wv[i - 2048 * 1024]);
  if (i < 1024 * 1024) wo_b[i] = f2bf(wo[i]);
}

// ---------------- LN1 (no affine) -> bf16, plus rel-embedding rows + zero pad ------------
__global__ __launch_bounds__(256) void k_ln1(const float* hid, const float* rel, ushort* h_ext) {
  int row = blockIdx.x, tid = threadIdx.x;
  __shared__ float red[8];
  if (row < NROWS) {
    const float* src = hid + (size_t)row * HID;
    f32x4 x = *(const f32x4*)(src + tid * 4);
    float s = x[0] + x[1] + x[2] + x[3];
    #pragma unroll
    for (int m = 1; m < 64; m <<= 1) s += __shfl_xor(s, m);
    if ((tid & 63) == 0) red[tid >> 6] = s;
    __syncthreads();
    float mean = (red[0] + red[1] + red[2] + red[3]) * (1.0f / HID);
    float d0 = x[0] - mean, d1 = x[1] - mean, d2 = x[2] - mean, d3 = x[3] - mean;
    float sq = d0*d0 + d1*d1 + d2*d2 + d3*d3;
    #pragma unroll
    for (int m = 1; m < 64; m <<= 1) sq += __shfl_xor(sq, m);
    __syncthreads();
    if ((tid & 63) == 0) red[4 + (tid >> 6)] = sq;
    __syncthreads();
    float var = (red[4] + red[5] + red[6] + red[7]) * (1.0f / HID);
    float rs = rsqrtf(var + LNEPS);
    u16x4 o = { f2bf(d0*rs), f2bf(d1*rs), f2bf(d2*rs), f2bf(d3*rs) };
    *(u16x4*)(h_ext + (size_t)row * HID + tid * 4) = o;
  } else if (row < NROWS + RELN) {
    const float* src = rel + (size_t)(row - NROWS) * HID;
    f32x4 x = *(const f32x4*)(src + tid * 4);
    u16x4 o = { f2bf(x[0]), f2bf(x[1]), f2bf(x[2]), f2bf(x[3]) };
    *(u16x4*)(h_ext + (size_t)row * HID + tid * 4) = o;
  } else {
    u16x4 z = { 0, 0, 0, 0 };
    *(u16x4*)(h_ext + (size_t)row * HID + tid * 4) = z;
  }
}

// ---------------- NT GEMM: C[M,N] = A[M,K] * B[N,K]^T + bias, bf16 in, bf16/f32 out ------
// 128x128 tile, BK=64, global_load_lds(16B) with XOR-swizzled global source.
// 1D grid + XCD-chunked block swizzle (grid % 8 == 0).
template<int WRITE_F32>
__global__ __launch_bounds__(256) void k_gemm(const ushort* A, const ushort* Bw, const float* bias,
                                              ushort* Cb, float* Cf, int M, int N, int K) {
  __shared__ char smem[32768];
  char* As = smem;
  char* Bs = smem + 16384;
  int tid = threadIdx.x, lane = tid & 63, w = tid >> 6;
  int nbn = N >> 7;
  int per = gridDim.x >> 3;
  int gl = (blockIdx.x & 7) * per + (blockIdx.x >> 3);
  int bm = gl / nbn, bn = gl % nbn;
  int wr = w >> 1, wc = w & 1;
  int g = lane >> 4, r = lane & 15;
  f32x4 acc[4][4] = {};
  for (int ko = 0; ko < K; ko += 64) {
    __syncthreads();
    #pragma unroll
    for (int c = 0; c < 4; ++c) {
      int chunk = c * 256 + tid;
      int row = chunk >> 3;
      int kb = (chunk & 7) << 4;
      int kbs = kb ^ ((row & 7) << 4);   // pre-swizzled source column (bytes)
      const char* gA = (const char*)(A + (size_t)(bm * 128 + row) * K + ko) + kbs;
      const char* gB = (const char*)(Bw + (size_t)(bn * 128 + row) * K + ko) + kbs;
      __builtin_amdgcn_global_load_lds((const __attribute__((address_space(1))) void*)gA,
                                       (__attribute__((address_space(3))) void*)(As + c * 4096 + w * 1024),
                                       16, 0, 0);
      __builtin_amdgcn_global_load_lds((const __attribute__((address_space(1))) void*)gB,
                                       (__attribute__((address_space(3))) void*)(Bs + c * 4096 + w * 1024),
                                       16, 0, 0);
    }
    __syncthreads();
    #pragma unroll
    for (int kk = 0; kk < 2; ++kk) {
      s16x8 af[4], bf[4];
      #pragma unroll
      for (int mt = 0; mt < 4; ++mt) {
        int row = wr * 64 + mt * 16 + r;
        int kb = (kk * 64 + g * 16) ^ ((row & 7) << 4);
        af[mt] = *(const s16x8*)(As + row * 128 + kb);
      }
      #pragma unroll
      for (int nt = 0; nt < 4; ++nt) {
        int row = wc * 64 + nt * 16 + r;
        int kb = (kk * 64 + g * 16) ^ ((row & 7) << 4);
        bf[nt] = *(const s16x8*)(Bs + row * 128 + kb);
      }
      #pragma unroll
      for (int mt = 0; mt < 4; ++mt)
        #pragma unroll
        for (int nt = 0; nt < 4; ++nt)
          acc[mt][nt] = __builtin_amdgcn_mfma_f32_16x16x32_bf16(af[mt], bf[nt], acc[mt][nt], 0, 0, 0);
    }
  }
  #pragma unroll
  for (int nt = 0; nt < 4; ++nt) {
    int col = bn * 128 + wc * 64 + nt * 16 + r;
    float bvv = bias[col];
    #pragma unroll
    for (int mt = 0; mt < 4; ++mt) {
      int row0 = bm * 128 + wr * 64 + mt * 16 + g * 4;
      #pragma unroll
      for (int i = 0; i < 4; ++i) {
        float v = acc[mt][nt][i] + bvv;
        if (WRITE_F32) Cf[(size_t)(row0 + i) * N + col] = v;
        else           Cb[(size_t)(row0 + i) * N + col] = f2bf(v);
      }
    }
  }
}

// ---------------- positional score tables (bf16, pre-scaled, mask baked into pk) ---------
__global__ __launch_bounds__(256) void k_pos(const ushort* qkv, const ushort* mask01,
                                             ushort* qp, ushort* pk) {
  int bh = blockIdx.x;
  int b = bh >> 4, h = bh & 15;
  int tid = threadIdx.x, lane = tid & 63, w = tid >> 6;
  int g = lane >> 4, r = lane & 15;
  __shared__ ushort mb[512];
  for (int i = tid; i < 512; i += 256) mb[i] = mask01[b * SEQ + i];
  __syncthreads();
  s16x8 bkp[4][2], bqp[4][2];   // kpos / qpos B-fragments (t = nt*16+r)
  #pragma unroll
  for (int nt = 0; nt < 4; ++nt)
    #pragma unroll
    for (int kk = 0; kk < 2; ++kk) {
      size_t rowp = (size_t)(NROWS + nt * 16 + r);
      int colq = h * 64 + kk * 32 + g * 8;
      bqp[nt][kk] = *(const s16x8*)(qkv + rowp * NQKV + colq);
      bkp[nt][kk] = *(const s16x8*)(qkv + rowp * NQKV + 1024 + colq);
    }
  for (int cc = 0; cc < 8; ++cc) {
    int rowbase = cc * 64 + w * 16;
    s16x8 aq[2], ak[2];
    #pragma unroll
    for (int kk = 0; kk < 2; ++kk) {
      size_t rowq = (size_t)((rowbase + r) * 16 + b);
      int colq = h * 64 + kk * 32 + g * 8;
      aq[kk] = *(const s16x8*)(qkv + rowq * NQKV + colq);
      ak[kk] = *(const s16x8*)(qkv + rowq * NQKV + 1024 + colq);
    }
    f32x4 accq[4] = {}, acck[4] = {};
    #pragma unroll
    for (int kk = 0; kk < 2; ++kk)
      #pragma unroll
      for (int nt = 0; nt < 4; ++nt) {
        accq[nt] = __builtin_amdgcn_mfma_f32_16x16x32_bf16(aq[kk], bkp[nt][kk], accq[nt], 0, 0, 0);
        acck[nt] = __builtin_amdgcn_mfma_f32_16x16x32_bf16(ak[kk], bqp[nt][kk], acck[nt], 0, 0, 0);
      }
    #pragma unroll
    for (int nt = 0; nt < 4; ++nt)
      #pragma unroll
      for (int i = 0; i < 4; ++i) {
        int q = rowbase + g * 4 + i;
        int t = nt * 16 + r;
        float biasv = mb[q] ? -1e9f : 0.0f;          // mask baked into pk rows
        qp[(size_t)bh * SEQ * 64 + q * 64 + t] = f2bf(accq[nt][i] * SCALEF);
        pk[(size_t)bh * SEQ * 64 + q * 64 + t] = f2bf(acck[nt][i] * SCALEF + biasv);
      }
  }
}

// ---------------- V transpose + K repack (K pre-scaled): vt[b,h,d,l], kc[b,h,l,d] --------
__global__ __launch_bounds__(256) void k_vt(const ushort* qkv, ushort* vt, ushort* kc) {
  int bid = blockIdx.x;
  int bh = bid >> 3, lt = bid & 7;
  int b = bh >> 4, h = bh & 15;
  __shared__ ushort tile[64][72];
  int tid = threadIdx.x;
  #pragma unroll
  for (int c = 0; c < 2; ++c) {
    int e = (c * 256 + tid) * 8;
    int l = e >> 6, d0 = e & 63;
    size_t row = (size_t)((lt * 64 + l) * 16 + b);
    s16x8 kv = *(const s16x8*)(qkv + row * NQKV + 1024 + h * 64 + d0);
    #pragma unroll
    for (int j = 0; j < 8; ++j) kv[j] = (short)f2bf(bf2f((ushort)kv[j]) * SCALEF);
    *(s16x8*)(kc + ((size_t)bh * SEQ + lt * 64 + l) * 64 + d0) = kv;   // scaled K rows
    *(s16x8*)&tile[l][d0] = *(const s16x8*)(qkv + row * NQKV + 2048 + h * 64 + d0);
  }
  __syncthreads();
  #pragma unroll
  for (int c = 0; c < 2; ++c) {
    int e = (c * 256 + tid) * 8;
    int d = e >> 6, l0 = e & 63;
    ushort tmp[8];
    #pragma unroll
    for (int j = 0; j < 8; ++j) tmp[j] = tile[l0 + j][d];
    *(s16x8*)(vt + (size_t)(bh * 64 + d) * SEQ + lt * 64 + l0) = *(s16x8*)tmp;
  }
}

// ---------------- fused attention -------------------------------------------------------
// XCD-aware block map; single-buffer K (global_load_lds, swizzled) + single pk_s;
// staging issued right after the gather pass so exp/PV compute covers the vmcnt drain.
// Mask is pre-baked into pk table; scale pre-folded into kc + tables. LDS 36,864 B.
__global__ __launch_bounds__(256) void k_attn(const ushort* qkv, const ushort* qp_all, const ushort* pk_all,
                                              const ushort* kc, const ushort* vt,
                                              const int* idx_tab, ushort* ctx) {
  int bid = blockIdx.x;
  int slot = bid >> 3;
  int bh = (bid & 7) * 32 + (slot >> 3);   // all 8 qt-blocks of a bh on one XCD
  int qt = slot & 7;
  int b = bh >> 4, h = bh & 15;
  int tid = threadIdx.x, lane = tid & 63, w = tid >> 6;
  int g = lane >> 4, r = lane & 15;

  __shared__ char   Ks[8192];
  __shared__ ushort qp_s[64][72];
  __shared__ ushort pk_s[64][72];
  __shared__ ushort p_s[4][16][72];
  __shared__ unsigned char idx_s[1024];

  const size_t qp_base = (size_t)bh * SEQ * 64 + (size_t)qt * 4096;
  const size_t pk_base = (size_t)bh * SEQ * 64;
  const char* kcb = (const char*)(kc + (size_t)bh * SEQ * 64);   // [l][d] 128B rows

  int krow = w * 8 + (lane >> 3);                   // staging row (+c*32)
  int ksrccol = ((lane & 7) ^ (lane >> 3)) << 4;    // pre-swizzled source col (bytes)

  // ---- prologue: stage K(0), pk(0)->regs, qp->LDS, idx, aq ----
  #pragma unroll
  for (int c = 0; c < 2; ++c) {
    const char* src = kcb + (size_t)(c * 32 + krow) * 128 + ksrccol;
    __builtin_amdgcn_global_load_lds((const __attribute__((address_space(1))) void*)src,
                                     (__attribute__((address_space(3))) void*)(Ks + c * 4096 + w * 1024),
                                     16, 0, 0);
  }
  s16x8 pkreg[2];
  #pragma unroll
  for (int c = 0; c < 2; ++c)
    pkreg[c] = *(const s16x8*)(pk_all + pk_base + (size_t)(c * 256 + tid) * 8);
  #pragma unroll
  for (int c = 0; c < 2; ++c) {
    int chunk = c * 256 + tid;
    s16x8 v = *(const s16x8*)(qp_all + qp_base + (size_t)chunk * 8);
    *(s16x8*)&qp_s[chunk >> 3][(chunk & 7) * 8] = v;
  }
  for (int i = tid; i < 1023; i += 256) idx_s[i] = (unsigned char)idx_tab[i];
  s16x8 aq[2];
  int qg0 = qt * 64 + w * 16;
  #pragma unroll
  for (int kk = 0; kk < 2; ++kk) {
    size_t row = (size_t)((qg0 + r) * 16 + b);
    aq[kk] = *(const s16x8*)(qkv + row * NQKV + h * 64 + kk * 32 + g * 8);
  }
  #pragma unroll
  for (int c = 0; c < 2; ++c) {
    int chunk = c * 256 + tid;
    *(s16x8*)&pk_s[chunk >> 3][(chunk & 7) * 8] = pkreg[c];
  }
  __syncthreads();   // drains K(0) staging too

  float m_i[4], l_i[4];
  f32x4 o_acc[4] = {};
  #pragma unroll
  for (int i = 0; i < 4; ++i) { m_i[i] = -3e38f; l_i[i] = 0.0f; }

  for (int kt = 0; kt < 8; ++kt) {
    // prefetch pk(kt+1) into regs (consumed after barrier A)
    if (kt < 7) {
      #pragma unroll
      for (int c = 0; c < 2; ++c)
        pkreg[c] = *(const s16x8*)(pk_all + pk_base + (size_t)(kt + 1) * 4096 + (size_t)(c * 256 + tid) * 8);
    }

    // ---- QK^T from swizzled LDS K (pre-scaled) ----
    f32x4 s[4];
    #pragma unroll
    for (int nt = 0; nt < 4; ++nt) {
      f32x4 a = {};
      #pragma unroll
      for (int kk = 0; kk < 2; ++kk) {
        s16x8 bk = *(const s16x8*)(Ks + (nt * 16 + r) * 128 + ((kk * 64 + g * 16) ^ ((r & 7) << 4)));
        a = __builtin_amdgcn_mfma_f32_16x16x32_bf16(aq[kk], bk, a, 0, 0, 0);
      }
      s[nt] = a;
    }

    // ---- gather pass: v = c2c + qp[q][t] + pk[k][t] (mask+scale pre-baked) ----
    float tilemax[4];
    #pragma unroll
    for (int i = 0; i < 4; ++i) tilemax[i] = -3e38f;
    #pragma unroll
    for (int nt = 0; nt < 4; ++nt) {
      int kl = nt * 16 + r;
      int kgl = kt * 64 + kl;
      #pragma unroll
      for (int i = 0; i < 4; ++i) {
        int ql = w * 16 + g * 4 + i;
        int t = idx_s[(qt * 64 + ql) - kgl + 511];
        float v = s[nt][i] + bf2f(qp_s[ql][t]) + bf2f(pk_s[kl][t]);
        s[nt][i] = v;
        tilemax[i] = fmaxf(tilemax[i], v);
      }
    }
    __syncthreads();   // A: all waves done reading Ks + pk_s

    // ---- issue next-tile staging; exp/PV below covers the latency ----
    if (kt < 7) {
      #pragma unroll
      for (int c = 0; c < 2; ++c) {
        const char* src = kcb + (size_t)(kt + 1) * 8192 + (size_t)(c * 32 + krow) * 128 + ksrccol;
        __builtin_amdgcn_global_load_lds((const __attribute__((address_space(1))) void*)src,
                                         (__attribute__((address_space(3))) void*)(Ks + c * 4096 + w * 1024),
                                         16, 0, 0);
      }
      #pragma unroll
      for (int c = 0; c < 2; ++c) {
        int chunk = c * 256 + tid;
        *(s16x8*)&pk_s[chunk >> 3][(chunk & 7) * 8] = pkreg[c];
      }
    }
    // V loads for this tile
    s16x8 vreg[2][4];
    #pragma unroll
    for (int kk = 0; kk < 2; ++kk)
      #pragma unroll
      for (int nt = 0; nt < 4; ++nt)
        vreg[kk][nt] = *(const s16x8*)(vt + (size_t)(bh * 64 + nt * 16 + r) * SEQ + kt * 64 + kk * 32 + g * 8);

    // ---- softmax finish ----
    #pragma unroll
    for (int i = 0; i < 4; ++i) {
      float v = tilemax[i];
      v = fmaxf(v, __shfl_xor(v, 1));
      v = fmaxf(v, __shfl_xor(v, 2));
      v = fmaxf(v, __shfl_xor(v, 4));
      v = fmaxf(v, __shfl_xor(v, 8));
      tilemax[i] = v;
    }
    float rs_i[4], psum[4];
    #pragma unroll
    for (int i = 0; i < 4; ++i) {
      float mnew = fmaxf(m_i[i], tilemax[i]);
      rs_i[i] = __expf(m_i[i] - mnew);
      m_i[i] = mnew;
      l_i[i] *= rs_i[i];
      psum[i] = 0.0f;
    }
    #pragma unroll
    for (int nt = 0; nt < 4; ++nt)
      #pragma unroll
      for (int i = 0; i < 4; ++i) {
        float pe = __expf(s[nt][i] - m_i[i]);   // masked: ~-1e9-m -> exact 0
        psum[i] += pe;
        p_s[w][g * 4 + i][nt * 16 + r] = f2bf(pe);
      }
    #pragma unroll
    for (int i = 0; i < 4; ++i) {
      float v = psum[i];
      v += __shfl_xor(v, 1);
      v += __shfl_xor(v, 2);
      v += __shfl_xor(v, 4);
      v += __shfl_xor(v, 8);
      l_i[i] += v;
    }
    #pragma unroll
    for (int nt = 0; nt < 4; ++nt)
      #pragma unroll
      for (int i = 0; i < 4; ++i) o_acc[nt][i] *= rs_i[i];

    // ---- PV ----
    #pragma unroll
    for (int kk = 0; kk < 2; ++kk) {
      s16x8 pa = *(const s16x8*)&p_s[w][r][kk * 32 + g * 8];
      #pragma unroll
      for (int nt = 0; nt < 4; ++nt)
        o_acc[nt] = __builtin_amdgcn_mfma_f32_16x16x32_bf16(pa, vreg[kk][nt], o_acc[nt], 0, 0, 0);
    }

    if (kt < 7) __syncthreads();   // B: staging + pk_s(kt+1) visible (vmcnt drain overlapped)
  }

  #pragma unroll
  for (int i = 0; i < 4; ++i) {
    float inv = l_i[i] > 0.0f ? 1.0f / l_i[i] : 0.0f;
    int lq = qt * 64 + w * 16 + g * 4 + i;
    size_t rowc = (size_t)(lq * 16 + b);
    #pragma unroll
    for (int nt = 0; nt < 4; ++nt)
      ctx[rowc * HID + h * 64 + nt * 16 + r] = f2bf(o_acc[nt][i] * inv);
  }
}

// ---------------- LN2 (affine) -> f32 out -------------------------------------------------
__global__ __launch_bounds__(256) void k_ln2(const float* tmp, const float* gamma, const float* beta,
                                             float* out) {
  int row = blockIdx.x, tid = threadIdx.x;
  __shared__ float red[8];
  const float* src = tmp + (size_t)row * HID;
  f32x4 x = *(const f32x4*)(src + tid * 4);
  float s = x[0] + x[1] + x[2] + x[3];
  #pragma unroll
  for (int m = 1; m < 64; m <<= 1) s += __shfl_xor(s, m);
  if ((tid & 63) == 0) red[tid >> 6] = s;
  __syncthreads();
  float mean = (red[0] + red[1] + red[2] + red[3]) * (1.0f / HID);
  float d[4]; float sq = 0.0f;
  #pragma unroll
  for (int j = 0; j < 4; ++j) { d[j] = x[j] - mean; sq += d[j] * d[j]; }
  #pragma unroll
  for (int m = 1; m < 64; m <<= 1) sq += __shfl_xor(sq, m);
  __syncthreads();
  if ((tid & 63) == 0) red[4 + (tid >> 6)] = sq;
  __syncthreads();
  float var = (red[4] + red[5] + red[6] + red[7]) * (1.0f / HID);
  float rs = rsqrtf(var + LNEPS);
  f32x4 o;
  #pragma unroll
  for (int j = 0; j < 4; ++j) o[j] = d[j] * rs * gamma[tid * 4 + j] + beta[tid * 4 + j];
  *(f32x4*)(out + (size_t)row * HID + tid * 4) = o;
}

// ---------------- launch -----------------------------------------------------------------
extern "C" void kernel_launch(void* const* d_in, const int* in_sizes, int n_in,
                              void* d_out, int out_size, void* d_ws, size_t ws_size,
                              hipStream_t stream) {
  (void)in_sizes; (void)n_in; (void)out_size; (void)ws_size;
  const float* hid  = (const float*)d_in[0];
  const void*  mask = d_in[1];
  const float* rel  = (const float*)d_in[2];
  const float* wqk  = (const float*)d_in[3];
  const float* bqk  = (const float*)d_in[4];
  const float* wv   = (const float*)d_in[5];
  const float* bv   = (const float*)d_in[6];
  const float* wo   = (const float*)d_in[7];
  const float* bo   = (const float*)d_in[8];
  const float* ln_g = (const float*)d_in[9];
  const float* ln_b = (const float*)d_in[10];

  char* ws = (char*)d_ws;
  ushort* wcat     = (ushort*)(ws);                 //  6,291,456
  ushort* wo_b     = (ushort*)(ws + 6291456);       //  2,097,152
  float*  bcat     = (float*) (ws + 8388608);       //     12,288
  ushort* mask01   = (ushort*)(ws + 8400896);       //     16,384 (region 32,768)
  int*    idx_tab  = (int*)   (ws + 8433664);       //      4,096
  ushort* h_ext    = (ushort*)(ws + 8437760);       // 17,039,360  (reused as ctx)
  ushort* qkv      = (ushort*)(ws + 25477120);      // 51,118,080
  ushort* qp_b     = (ushort*)(ws + 76595200);      // 16,777,216 (bf16, pre-scaled)
  ushort* pk_b     = (ushort*)(ws + 93372416);      // 16,777,216 (bf16, pre-scaled + mask)
  ushort* vt       = (ushort*)(ws + 110149632);     // 16,777,216
  float*  tmp      = (float*) (ws + 126926848);     // 33,554,432  -> total 160,481,280
  ushort* ctx = h_ext;
  ushort* kc  = (ushort*)tmp;   // kc[bh][l][d] (scaled) lives in tmp (dead until gemm<1>)

  k_prep<<<1, 256, 0, stream>>>(mask, bqk, bv, mask01, idx_tab, bcat);
  k_convert<<<12288, 256, 0, stream>>>(wqk, wv, wo, wcat, wo_b);
  k_ln1<<<MEXT, 256, 0, stream>>>(hid, rel, h_ext);
  k_gemm<0><<<(MEXT / 128) * (NQKV / 128), 256, 0, stream>>>(h_ext, wcat, bcat, qkv, nullptr, MEXT, NQKV, 1024);
  k_pos<<<256, 256, 0, stream>>>(qkv, mask01, qp_b, pk_b);
  k_vt<<<2048, 256, 0, stream>>>(qkv, vt, kc);
  k_attn<<<2048, 256, 0, stream>>>(qkv, qp_b, pk_b, kc, vt, idx_tab, ctx);
  k_gemm<1><<<(NROWS / 128) * (1024 / 128), 256, 0, stream>>>(ctx, wo_b, bo, nullptr, tmp, NROWS, 1024, 1024);
  k_ln2<<<NROWS, 256, 0, stream>>>(tmp, ln_g, ln_b, (float*)d_out);
}